// Round 4
// baseline (109.858 us; speedup 1.0000x reference)
//
#include <hip/hip_runtime.h>
#include <math.h>

#define IMG_S 256
#define NPIX (IMG_S * IMG_S)
#define NFACE 500
#define NFACEPAD 512         // padded with inert faces (C=-1 -> never inside)
#define NCHUNK 8
#define FPC 64               // NFACEPAD / NCHUNK, compile-time trip count
#define PPT 8                // pixels (rows) per thread
#define TSZ 6
#define DIST 2.732f
#define CSTRIDE 16           // floats per face in coef table (12 used, 16 for alignment)

// coef layout per face (16 floats):
//  [0]=A0 [1]=B0 [2]=C0  [3]=A1 [4]=B1 [5]=C1  [6]=A2 [7]=B2 [8]=C2
//  [9]=Az [10]=Bz [11]=Cz  [12..15]=pad
// w_i = A_i*px + B_i*py + C_i   (edge fn pre-multiplied by 1/area)
// z   = Az*px + Bz*py + Cz

struct FaceCoef {
    float A0, B0, C0, A1, B1, C1, A2, B2, C2, Az, Bz, Cz;
};

__device__ __forceinline__ void edge_coef(float ax, float ay, float bx, float by,
                                          float inv, float& A, float& B, float& C) {
    float dy = by - ay;
    float dx = bx - ax;
    A = dy * inv;
    B = -dx * inv;
    C = (ay * dx - ax * dy) * inv;
}

__device__ __forceinline__ FaceCoef compute_face(const float* __restrict__ verts,
                                                 const int* __restrict__ faces,
                                                 int f, int view) {
    int i0 = faces[f * 3 + 0];
    int i1 = faces[f * 3 + 1];
    int i2 = faces[f * 3 + 2];

    float v0x = verts[i0 * 3 + 0], v0y = verts[i0 * 3 + 1], v0z = verts[i0 * 3 + 2];
    float v1x = verts[i1 * 3 + 0], v1y = verts[i1 * 3 + 1], v1z = verts[i1 * 3 + 2];
    float v2x = verts[i2 * 3 + 0], v2y = verts[i2 * 3 + 1], v2z = verts[i2 * 3 + 2];

    float p0x, p0y, p0z, p1x, p1y, p1z, p2x, p2y, p2z;
    if (view == 0) {
        // eye=(0,0,+D): v'=(-x, y, D-z)
        p0x = -v0x; p0y = v0y; p0z = DIST - v0z;
        p1x = -v1x; p1y = v1y; p1z = DIST - v1z;
        p2x = -v2x; p2y = v2y; p2z = DIST - v2z;
    } else {
        // eye=(0,0,-D): v'=(x, y, z+D)
        p0x = v0x; p0y = v0y; p0z = v0z + DIST;
        p1x = v1x; p1y = v1y; p1z = v1z + DIST;
        p2x = v2x; p2y = v2y; p2z = v2z + DIST;
    }

    float area = (p1x - p0x) * (p2y - p0y) - (p1y - p0y) * (p2x - p0x);
    bool ok = fabsf(area) > 1e-8f;

    FaceCoef fc;
    if (ok) {
        float inv = 1.0f / area;
        edge_coef(p1x, p1y, p2x, p2y, inv, fc.A0, fc.B0, fc.C0);  // e0 = edge(p1,p2)
        edge_coef(p2x, p2y, p0x, p0y, inv, fc.A1, fc.B1, fc.C1);  // e1 = edge(p2,p0)
        edge_coef(p0x, p0y, p1x, p1y, inv, fc.A2, fc.B2, fc.C2);  // e2 = edge(p0,p1)
        fc.Az = fc.A0 * p0z + fc.A1 * p1z + fc.A2 * p2z;
        fc.Bz = fc.B0 * p0z + fc.B1 * p1z + fc.B2 * p2z;
        fc.Cz = fc.C0 * p0z + fc.C1 * p1z + fc.C2 * p2z;
    } else {
        fc.A0 = fc.B0 = fc.A1 = fc.B1 = fc.A2 = fc.B2 = 0.0f;
        fc.C0 = fc.C1 = fc.C2 = -1.0f;   // inside-test always fails
        fc.Az = fc.Bz = fc.Cz = 0.0f;
    }
    return fc;
}

__device__ __forceinline__ float pix_x(int ix) {
    return (2.0f * (float)ix + 1.0f - (float)IMG_S) * (1.0f / (float)IMG_S);
}
__device__ __forceinline__ float pix_y(int iy) {
    return -((2.0f * (float)iy + 1.0f - (float)IMG_S) * (1.0f / (float)IMG_S));
}

// ---- Pass 0: face coefficients -> global table (once); zero the output scalar ----
__global__ __launch_bounds__(256) void setup_kernel(
    const float* __restrict__ verts,
    const int*   __restrict__ faces,
    float* __restrict__ coef,
    float* __restrict__ out)
{
    int gid = blockIdx.x * blockDim.x + threadIdx.x;   // 0..1023
    if (gid == 0) out[0] = 0.0f;                       // atomicAdd target (stream-ordered before shade)
    int view = gid >> 9;
    int f    = gid & (NFACEPAD - 1);

    FaceCoef c;
    if (f < NFACE) {
        c = compute_face(verts, faces, f, view);
    } else {
        c.A0 = c.B0 = c.A1 = c.B1 = c.A2 = c.B2 = 0.0f;
        c.C0 = c.C1 = c.C2 = -1.0f;                    // inert pad face
        c.Az = c.Bz = c.Cz = 0.0f;
    }
    float* p = coef + (size_t)(view * NFACEPAD + f) * CSTRIDE;
    p[0] = c.A0; p[1] = c.B0; p[2] = c.C0;
    p[3] = c.A1; p[4] = c.B1; p[5] = c.C1;
    p[6] = c.A2; p[7] = c.B2; p[8] = c.C2;
    p[9] = c.Az; p[10] = c.Bz; p[11] = c.Cz;
    p[12] = 0.0f; p[13] = 0.0f; p[14] = 0.0f; p[15] = 0.0f;
}

// ---- Pass 1: z-buffer per (view, chunk); coefs come in through the SCALAR path ----
// Address of coef is blockIdx/loop-uniform -> s_load into SGPRs; no LDS, no barrier.
__global__ __launch_bounds__(256) void raster_chunk_kernel(
    const float* __restrict__ coef,
    unsigned long long* __restrict__ packed_out)
{
    const int tile  = blockIdx.x;    // rows [tile*8, tile*8+8)
    const int chunk = blockIdx.y;
    const int view  = blockIdx.z;
    const int fbase = chunk * FPC;

    const float* __restrict__ cf = coef + (size_t)(view * NFACEPAD + fbase) * CSTRIDE;

    const int ix = threadIdx.x;      // column (256 threads = 256 columns)
    const float px = pix_x(ix);
    float py[PPT];
    #pragma unroll
    for (int k = 0; k < PPT; ++k) py[k] = pix_y(tile * PPT + k);

    float bestz[PPT];
    int   besti[PPT];
    #pragma unroll
    for (int k = 0; k < PPT; ++k) { bestz[k] = INFINITY; besti[k] = -1; }

    #pragma unroll 2
    for (int f = 0; f < FPC; ++f) {
        const float* c = cf + f * CSTRIDE;             // uniform -> scalar loads
        float B0 = c[1], B1 = c[4], B2 = c[7], Bz = c[10];
        // px-dependent part hoisted (per lane, once per face)
        float d0 = fmaf(px, c[0], c[2]);
        float d1 = fmaf(px, c[3], c[5]);
        float d2 = fmaf(px, c[6], c[8]);
        float dz = fmaf(px, c[9], c[11]);
        #pragma unroll
        for (int k = 0; k < PPT; ++k) {
            float w0 = fmaf(B0, py[k], d0);
            float w1 = fmaf(B1, py[k], d1);
            float w2 = fmaf(B2, py[k], d2);
            float z  = fmaf(Bz, py[k], dz);
            float wmin = fminf(w0, fminf(w1, w2));
            float s = fminf(z, bestz[k] - z);   // >0 iff z>0 && z<bestz (bestz>0 invariant)
            bool cc = (wmin >= 0.0f) && (s > 0.0f);
            bestz[k] = cc ? z : bestz[k];       // strict < keeps first index on ties
            besti[k] = cc ? f : besti[k];
        }
    }

    unsigned long long* __restrict__ outp =
        packed_out + (size_t)(view * NCHUNK + chunk) * NPIX + tile * (PPT * IMG_S) + ix;
    #pragma unroll
    for (int k = 0; k < PPT; ++k) {
        unsigned long long packed;
        if (besti[k] >= 0)
            packed = ((unsigned long long)__float_as_uint(bestz[k]) << 32) |
                     (unsigned int)(fbase + besti[k]);
        else
            packed = ~0ull;
        outp[k * IMG_S] = packed;
    }
}

// ---- Pass 2: merge chunks, shade winner (coefs from the SAME table -> bit-exact),
//              per-pixel loss, block partial, atomicAdd into out ----
__global__ __launch_bounds__(256) void shade_loss_kernel(
    const float* __restrict__ coef,
    const float* __restrict__ tex,
    const float* __restrict__ ref0,
    const float* __restrict__ ref1,
    const unsigned long long* __restrict__ packed_in,
    float* __restrict__ out)
{
    __shared__ float red[4];
    const int gid  = blockIdx.x * blockDim.x + threadIdx.x;  // 0..131071
    const int view = gid >> 16;
    const int pix  = gid & (NPIX - 1);

    const unsigned long long* p = packed_in + (size_t)view * NCHUNK * NPIX + pix;
    unsigned long long best = p[0];
    #pragma unroll
    for (int c = 1; c < NCHUNK; ++c) {
        unsigned long long v = p[(size_t)c * NPIX];
        best = (v < best) ? v : best;   // packed min == argmin w/ first-idx ties
    }

    float c0 = 0.0f, c1 = 0.0f, c2 = 0.0f;
    if (best != ~0ull) {
        int fidx = (int)(best & 0xFFFFFFFFu);
        const float* c = coef + (size_t)(view * NFACEPAD + fidx) * CSTRIDE;
        const float px = pix_x(pix & (IMG_S - 1));
        const float py = pix_y(pix >> 8);
        // identical association as raster: fmaf(B, py, fmaf(px, A, C))
        float w0 = fmaf(c[1], py, fmaf(px, c[0], c[2]));
        float w1 = fmaf(c[4], py, fmaf(px, c[3], c[5]));
        float w2 = fmaf(c[7], py, fmaf(px, c[6], c[8]));
        int t0 = (int)fminf(fmaxf(rintf(w0 * (float)(TSZ - 1)), 0.0f), (float)(TSZ - 1));
        int t1 = (int)fminf(fmaxf(rintf(w1 * (float)(TSZ - 1)), 0.0f), (float)(TSZ - 1));
        int t2 = (int)fminf(fmaxf(rintf(w2 * (float)(TSZ - 1)), 0.0f), (float)(TSZ - 1));
        int flat = ((fidx * TSZ + t0) * TSZ + t1) * TSZ + t2;
        const float* t = tex + (long)flat * 3;
        c0 = tanhf(t[0]);
        c1 = tanhf(t[1]);
        c2 = tanhf(t[2]);
    }

    const float* __restrict__ ref = (view == 0) ? ref0 : ref1;
    float d0 = c0 - ref[0 * NPIX + pix];
    float d1 = c1 - ref[1 * NPIX + pix];
    float d2 = c2 - ref[2 * NPIX + pix];
    float acc = fmaf(d0, d0, fmaf(d1, d1, d2 * d2));

    for (int off = 32; off > 0; off >>= 1)
        acc += __shfl_down(acc, off, 64);
    int lane = threadIdx.x & 63;
    int wid = threadIdx.x >> 6;
    if (lane == 0) red[wid] = acc;
    __syncthreads();
    if (threadIdx.x == 0)
        atomicAdd(out, 0.5f * (red[0] + red[1] + red[2] + red[3]));
}

extern "C" void kernel_launch(void* const* d_in, const int* in_sizes, int n_in,
                              void* d_out, int out_size, void* d_ws, size_t ws_size,
                              hipStream_t stream) {
    const float* verts = (const float*)d_in[0];
    const int*   faces = (const int*)d_in[1];
    const float* tex   = (const float*)d_in[2];
    const float* ref0  = (const float*)d_in[3];
    const float* ref1  = (const float*)d_in[4];
    float* out = (float*)d_out;

    float* coef = (float*)d_ws;                                  // 2*512*16*4 = 64 KB
    unsigned long long* packed =
        (unsigned long long*)((char*)d_ws + (size_t)2 * NFACEPAD * CSTRIDE * 4);  // 8 MB

    setup_kernel<<<4, 256, 0, stream>>>(verts, faces, coef, out);

    dim3 grid1(NPIX / (256 * PPT), NCHUNK, 2);   // (32, 8, 2) = 512 blocks
    raster_chunk_kernel<<<grid1, 256, 0, stream>>>(coef, packed);

    const int shade_blocks = (2 * NPIX) / 256;   // 512
    shade_loss_kernel<<<shade_blocks, 256, 0, stream>>>(coef, tex, ref0, ref1,
                                                        packed, out);
}

// Round 5
// 90.757 us; speedup vs baseline: 1.2105x; 1.2105x over previous
//
#include <hip/hip_runtime.h>
#include <math.h>

#define IMG_S 256
#define NPIX (IMG_S * IMG_S)
#define NFACE 500
#define NCHUNK 16
#define FPC 32               // faces per chunk (padded to 512 with inert faces)
#define PPT 8                // pixels (rows) per thread
#define TSZ 6
#define DIST 2.732f

// w_i = A_i*px + B_i*py + C_i  (edge fn pre-multiplied by 1/area)
// z   = Az*px + Bz*py + Cz
struct FaceCoef {
    float A0, B0, C0, A1, B1, C1, A2, B2, C2, Az, Bz, Cz;
};

__device__ __forceinline__ void edge_coef(float ax, float ay, float bx, float by,
                                          float inv, float& A, float& B, float& C) {
    float dy = by - ay;
    float dx = bx - ax;
    A = dy * inv;
    B = -dx * inv;
    C = (ay * dx - ax * dy) * inv;
}

// IDENTICAL helper used by raster setup and shade -> bit-exact w agreement
// (verified: absmax 0.0 in R2/R3 with this recompute scheme).
__device__ __forceinline__ FaceCoef compute_face(const float* __restrict__ verts,
                                                 const int* __restrict__ faces,
                                                 int f, int view) {
    int i0 = faces[f * 3 + 0];
    int i1 = faces[f * 3 + 1];
    int i2 = faces[f * 3 + 2];

    float v0x = verts[i0 * 3 + 0], v0y = verts[i0 * 3 + 1], v0z = verts[i0 * 3 + 2];
    float v1x = verts[i1 * 3 + 0], v1y = verts[i1 * 3 + 1], v1z = verts[i1 * 3 + 2];
    float v2x = verts[i2 * 3 + 0], v2y = verts[i2 * 3 + 1], v2z = verts[i2 * 3 + 2];

    float p0x, p0y, p0z, p1x, p1y, p1z, p2x, p2y, p2z;
    if (view == 0) {
        // eye=(0,0,+D): v'=(-x, y, D-z)
        p0x = -v0x; p0y = v0y; p0z = DIST - v0z;
        p1x = -v1x; p1y = v1y; p1z = DIST - v1z;
        p2x = -v2x; p2y = v2y; p2z = DIST - v2z;
    } else {
        // eye=(0,0,-D): v'=(x, y, z+D)
        p0x = v0x; p0y = v0y; p0z = v0z + DIST;
        p1x = v1x; p1y = v1y; p1z = v1z + DIST;
        p2x = v2x; p2y = v2y; p2z = v2z + DIST;
    }

    float area = (p1x - p0x) * (p2y - p0y) - (p1y - p0y) * (p2x - p0x);
    bool ok = fabsf(area) > 1e-8f;

    FaceCoef fc;
    if (ok) {
        float inv = 1.0f / area;
        edge_coef(p1x, p1y, p2x, p2y, inv, fc.A0, fc.B0, fc.C0);  // e0 = edge(p1,p2)
        edge_coef(p2x, p2y, p0x, p0y, inv, fc.A1, fc.B1, fc.C1);  // e1 = edge(p2,p0)
        edge_coef(p0x, p0y, p1x, p1y, inv, fc.A2, fc.B2, fc.C2);  // e2 = edge(p0,p1)
        fc.Az = fc.A0 * p0z + fc.A1 * p1z + fc.A2 * p2z;
        fc.Bz = fc.B0 * p0z + fc.B1 * p1z + fc.B2 * p2z;
        fc.Cz = fc.C0 * p0z + fc.C1 * p1z + fc.C2 * p2z;
    } else {
        fc.A0 = fc.B0 = fc.A1 = fc.B1 = fc.A2 = fc.B2 = 0.0f;
        fc.C0 = fc.C1 = fc.C2 = -1.0f;   // inside-test always fails
        fc.Az = fc.Bz = fc.Cz = 0.0f;
    }
    return fc;
}

__device__ __forceinline__ float pix_x(int ix) {
    return (2.0f * (float)ix + 1.0f - (float)IMG_S) * (1.0f / (float)IMG_S);
}
__device__ __forceinline__ float pix_y(int iy) {
    return -((2.0f * (float)iy + 1.0f - (float)IMG_S) * (1.0f / (float)IMG_S));
}

// ---- Pass 1: per-(view,chunk) z-buffer; LDS coefs + register prefetch ----
// 1024 blocks (4/CU, 4 waves/SIMD) for latency hiding; 8 rows per thread
// amortize the 3 ds_read_b128 per face over 8 pixels.
__global__ __launch_bounds__(256) void raster_chunk_kernel(
    const float* __restrict__ verts,
    const int*   __restrict__ faces,
    unsigned long long* __restrict__ packed_out)
{
    __shared__ float4 fc[FPC][3];
    const int tile  = blockIdx.x;    // rows [tile*8, tile*8+8)
    const int chunk = blockIdx.y;
    const int view  = blockIdx.z;
    const int fbase = chunk * FPC;

    if ((int)threadIdx.x < FPC) {
        int f = fbase + (int)threadIdx.x;
        FaceCoef c;
        if (f < NFACE) {
            c = compute_face(verts, faces, f, view);
        } else {
            c.A0 = c.B0 = c.A1 = c.B1 = c.A2 = c.B2 = 0.0f;
            c.C0 = c.C1 = c.C2 = -1.0f;      // inert pad face
            c.Az = c.Bz = c.Cz = 0.0f;
        }
        fc[threadIdx.x][0] = make_float4(c.A0, c.B0, c.C0, c.A1);
        fc[threadIdx.x][1] = make_float4(c.B1, c.C1, c.A2, c.B2);
        fc[threadIdx.x][2] = make_float4(c.C2, c.Az, c.Bz, c.Cz);
    }
    __syncthreads();

    const int ix = threadIdx.x;      // column (256 threads = 256 columns)
    const float px = pix_x(ix);
    float py[PPT];
    #pragma unroll
    for (int k = 0; k < PPT; ++k) py[k] = pix_y(tile * PPT + k);

    float bestz[PPT];
    int   besti[PPT];
    #pragma unroll
    for (int k = 0; k < PPT; ++k) { bestz[k] = INFINITY; besti[k] = -1; }

    // register prefetch pipeline: face f+1's coefs load while face f computes
    float4 n0 = fc[0][0], n1 = fc[0][1], n2 = fc[0][2];
    #pragma unroll 4
    for (int f = 0; f < FPC; ++f) {
        float4 q0 = n0, q1 = n1, q2 = n2;
        int fn = (f + 1) & (FPC - 1);         // wraps to 0 on last iter (harmless)
        n0 = fc[fn][0]; n1 = fc[fn][1]; n2 = fc[fn][2];

        // hoist the px-dependent part (per-lane, once per face)
        float d0 = fmaf(px, q0.x, q0.z);   // A0*px + C0
        float d1 = fmaf(px, q0.w, q1.y);   // A1*px + C1
        float d2 = fmaf(px, q1.z, q2.x);   // A2*px + C2
        float dz = fmaf(px, q2.y, q2.w);   // Az*px + Cz
        #pragma unroll
        for (int k = 0; k < PPT; ++k) {
            float w0 = fmaf(q0.y, py[k], d0);
            float w1 = fmaf(q1.x, py[k], d1);
            float w2 = fmaf(q1.w, py[k], d2);
            float z  = fmaf(q2.z, py[k], dz);
            float wmin = fminf(w0, fminf(w1, w2));   // v_min3
            float s = fminf(z, bestz[k] - z);        // >0 iff z>0 && z<bestz
            bool cc = (wmin >= 0.0f) && (s > 0.0f);
            bestz[k] = cc ? z : bestz[k];            // strict < keeps first idx on ties
            besti[k] = cc ? f : besti[k];
        }
    }

    unsigned long long* __restrict__ outp =
        packed_out + (size_t)(view * NCHUNK + chunk) * NPIX + tile * (PPT * IMG_S) + ix;
    #pragma unroll
    for (int k = 0; k < PPT; ++k) {
        unsigned long long packed;
        if (besti[k] >= 0)
            packed = ((unsigned long long)__float_as_uint(bestz[k]) << 32) |
                     (unsigned int)(fbase + besti[k]);
        else
            packed = ~0ull;
        outp[k * IMG_S] = packed;
    }
}

// ---- Pass 2: merge 16 chunk planes, shade winner (bit-exact recompute),
//              per-pixel loss, block partials ----
__global__ __launch_bounds__(256) void shade_loss_kernel(
    const float* __restrict__ verts,
    const int*   __restrict__ faces,
    const float* __restrict__ tex,
    const float* __restrict__ ref0,
    const float* __restrict__ ref1,
    const unsigned long long* __restrict__ packed_in,
    float* __restrict__ partials)
{
    __shared__ float red[4];
    const int gid  = blockIdx.x * blockDim.x + threadIdx.x;  // 0..131071
    const int view = gid >> 16;
    const int pix  = gid & (NPIX - 1);

    const unsigned long long* p = packed_in + (size_t)view * NCHUNK * NPIX + pix;
    unsigned long long best = p[0];
    #pragma unroll
    for (int c = 1; c < NCHUNK; ++c) {
        unsigned long long v = p[(size_t)c * NPIX];
        best = (v < best) ? v : best;   // packed min == argmin w/ first-idx ties
    }

    float c0 = 0.0f, c1 = 0.0f, c2 = 0.0f;
    if (best != ~0ull) {
        int fidx = (int)(best & 0xFFFFFFFFu);
        FaceCoef fcw = compute_face(verts, faces, fidx, view);
        const float px = pix_x(pix & (IMG_S - 1));
        const float py = pix_y(pix >> 8);
        // same association as raster inner loop: fmaf(B, py, fmaf(px, A, C))
        float w0 = fmaf(fcw.B0, py, fmaf(px, fcw.A0, fcw.C0));
        float w1 = fmaf(fcw.B1, py, fmaf(px, fcw.A1, fcw.C1));
        float w2 = fmaf(fcw.B2, py, fmaf(px, fcw.A2, fcw.C2));
        int t0 = (int)fminf(fmaxf(rintf(w0 * (float)(TSZ - 1)), 0.0f), (float)(TSZ - 1));
        int t1 = (int)fminf(fmaxf(rintf(w1 * (float)(TSZ - 1)), 0.0f), (float)(TSZ - 1));
        int t2 = (int)fminf(fmaxf(rintf(w2 * (float)(TSZ - 1)), 0.0f), (float)(TSZ - 1));
        int flat = ((fidx * TSZ + t0) * TSZ + t1) * TSZ + t2;
        const float* t = tex + (long)flat * 3;
        c0 = tanhf(t[0]);
        c1 = tanhf(t[1]);
        c2 = tanhf(t[2]);
    }

    const float* __restrict__ ref = (view == 0) ? ref0 : ref1;
    float d0 = c0 - ref[0 * NPIX + pix];
    float d1 = c1 - ref[1 * NPIX + pix];
    float d2 = c2 - ref[2 * NPIX + pix];
    float acc = fmaf(d0, d0, fmaf(d1, d1, d2 * d2));

    for (int off = 32; off > 0; off >>= 1)
        acc += __shfl_down(acc, off, 64);
    int lane = threadIdx.x & 63;
    int wid = threadIdx.x >> 6;
    if (lane == 0) red[wid] = acc;
    __syncthreads();
    if (threadIdx.x == 0)
        partials[blockIdx.x] = red[0] + red[1] + red[2] + red[3];
}

__global__ __launch_bounds__(256) void reduce_kernel(const float* __restrict__ partials,
                                                     int n, float* __restrict__ out) {
    __shared__ float red[4];
    float v = 0.0f;
    for (int i = threadIdx.x; i < n; i += 256) v += partials[i];
    for (int off = 32; off > 0; off >>= 1)
        v += __shfl_down(v, off, 64);
    int lane = threadIdx.x & 63;
    int wid = threadIdx.x >> 6;
    if (lane == 0) red[wid] = v;
    __syncthreads();
    if (threadIdx.x == 0)
        out[0] = 0.5f * (red[0] + red[1] + red[2] + red[3]);
}

extern "C" void kernel_launch(void* const* d_in, const int* in_sizes, int n_in,
                              void* d_out, int out_size, void* d_ws, size_t ws_size,
                              hipStream_t stream) {
    const float* verts = (const float*)d_in[0];
    const int*   faces = (const int*)d_in[1];
    const float* tex   = (const float*)d_in[2];
    const float* ref0  = (const float*)d_in[3];
    const float* ref1  = (const float*)d_in[4];
    float* out = (float*)d_out;

    unsigned long long* packed = (unsigned long long*)d_ws;  // 2*16*65536*8 = 16 MB
    float* partials = (float*)((char*)d_ws + (size_t)2 * NCHUNK * NPIX * 8);

    dim3 grid1(NPIX / (256 * PPT), NCHUNK, 2);   // (32, 16, 2) = 1024 blocks
    raster_chunk_kernel<<<grid1, 256, 0, stream>>>(verts, faces, packed);

    const int shade_blocks = (2 * NPIX) / 256;   // 512
    shade_loss_kernel<<<shade_blocks, 256, 0, stream>>>(verts, faces, tex, ref0, ref1,
                                                        packed, partials);
    reduce_kernel<<<1, 256, 0, stream>>>(partials, shade_blocks, out);
}

// Round 6
// 87.954 us; speedup vs baseline: 1.2490x; 1.0319x over previous
//
#include <hip/hip_runtime.h>
#include <math.h>

#define IMG_S 256
#define NPIX (IMG_S * IMG_S)
#define NFACE 500
#define NCHUNK 16
#define FPC 32               // faces per chunk (16*32 = 512 >= 500)
#define PPT 8                // pixels (rows) per thread
#define TSZ 6
#define DIST 2.732f

// w_i = A_i*px + B_i*py + C_i  (edge fn pre-multiplied by 1/area)
// z   = Az*px + Bz*py + Cz
struct FaceCoef {
    float A0, B0, C0, A1, B1, C1, A2, B2, C2, Az, Bz, Cz;
};

__device__ __forceinline__ void edge_coef(float ax, float ay, float bx, float by,
                                          float inv, float& A, float& B, float& C) {
    float dy = by - ay;
    float dx = bx - ax;
    A = dy * inv;
    B = -dx * inv;
    C = (ay * dx - ax * dy) * inv;
}

// Single shared helper for raster-setup AND shade -> bit-exact agreement
// (same scheme verified absmax 0.0 in R2/R3/R5). Also returns bbox info.
__device__ __forceinline__ bool compute_face_bbox(const float* __restrict__ verts,
                                                  const int* __restrict__ faces,
                                                  int f, int view, FaceCoef& fc,
                                                  float& ymin, float& ymax, float& zmax) {
    int i0 = faces[f * 3 + 0];
    int i1 = faces[f * 3 + 1];
    int i2 = faces[f * 3 + 2];

    float v0x = verts[i0 * 3 + 0], v0y = verts[i0 * 3 + 1], v0z = verts[i0 * 3 + 2];
    float v1x = verts[i1 * 3 + 0], v1y = verts[i1 * 3 + 1], v1z = verts[i1 * 3 + 2];
    float v2x = verts[i2 * 3 + 0], v2y = verts[i2 * 3 + 1], v2z = verts[i2 * 3 + 2];

    float p0x, p0y, p0z, p1x, p1y, p1z, p2x, p2y, p2z;
    if (view == 0) {
        // eye=(0,0,+D): v'=(-x, y, D-z)
        p0x = -v0x; p0y = v0y; p0z = DIST - v0z;
        p1x = -v1x; p1y = v1y; p1z = DIST - v1z;
        p2x = -v2x; p2y = v2y; p2z = DIST - v2z;
    } else {
        // eye=(0,0,-D): v'=(x, y, z+D)
        p0x = v0x; p0y = v0y; p0z = v0z + DIST;
        p1x = v1x; p1y = v1y; p1z = v1z + DIST;
        p2x = v2x; p2y = v2y; p2z = v2z + DIST;
    }

    ymin = fminf(p0y, fminf(p1y, p2y));
    ymax = fmaxf(p0y, fmaxf(p1y, p2y));
    zmax = fmaxf(p0z, fmaxf(p1z, p2z));

    float area = (p1x - p0x) * (p2y - p0y) - (p1y - p0y) * (p2x - p0x);
    bool ok = fabsf(area) > 1e-8f;
    if (!ok) return false;

    float inv = 1.0f / area;
    edge_coef(p1x, p1y, p2x, p2y, inv, fc.A0, fc.B0, fc.C0);  // e0 = edge(p1,p2)
    edge_coef(p2x, p2y, p0x, p0y, inv, fc.A1, fc.B1, fc.C1);  // e1 = edge(p2,p0)
    edge_coef(p0x, p0y, p1x, p1y, inv, fc.A2, fc.B2, fc.C2);  // e2 = edge(p0,p1)
    fc.Az = fc.A0 * p0z + fc.A1 * p1z + fc.A2 * p2z;
    fc.Bz = fc.B0 * p0z + fc.B1 * p1z + fc.B2 * p2z;
    fc.Cz = fc.C0 * p0z + fc.C1 * p1z + fc.C2 * p2z;
    return true;
}

__device__ __forceinline__ float pix_x(int ix) {
    return (2.0f * (float)ix + 1.0f - (float)IMG_S) * (1.0f / (float)IMG_S);
}
__device__ __forceinline__ float pix_y(int iy) {
    return -((2.0f * (float)iy + 1.0f - (float)IMG_S) * (1.0f / (float)IMG_S));
}

// ---- Pass 1: per-(view,chunk,slab) z-buffer with slab bbox cull + compaction;
//      winners merged globally via atomicMin(u64 packed (z,idx)) — order-free ----
__global__ __launch_bounds__(256) void raster_chunk_kernel(
    const float* __restrict__ verts,
    const int*   __restrict__ faces,
    unsigned long long* __restrict__ zbuf)   // [2][NPIX], pre-set to 0xFF..
{
    __shared__ float4 sc[FPC][3];
    __shared__ int    sidx[FPC];
    __shared__ int    scount;

    const int tile  = blockIdx.x;    // rows [tile*8, tile*8+8)
    const int chunk = blockIdx.y;
    const int view  = blockIdx.z;
    const int fbase = chunk * FPC;

    // slab py range (py decreases with row index)
    const float py_top = pix_y(tile * PPT);
    const float py_bot = pix_y(tile * PPT + PPT - 1);

    // ---- setup + cull + compact (first wave only) ----
    if (threadIdx.x < 64) {
        bool keep = false;
        FaceCoef c;
        int fi = fbase + (int)threadIdx.x;
        if ((int)threadIdx.x < FPC && fi < NFACE) {
            float ymin, ymax, zmax;
            bool ok = compute_face_bbox(verts, faces, fi, view, c, ymin, ymax, zmax);
            keep = ok && (ymax >= py_bot) && (ymin <= py_top) && (zmax > 0.0f);
        }
        unsigned long long bal = __ballot(keep);
        int pos = __popcll(bal & ((1ull << (threadIdx.x & 63)) - 1ull));
        if (keep) {
            sc[pos][0] = make_float4(c.A0, c.B0, c.C0, c.A1);
            sc[pos][1] = make_float4(c.B1, c.C1, c.A2, c.B2);
            sc[pos][2] = make_float4(c.C2, c.Az, c.Bz, c.Cz);
            sidx[pos] = fi;
        }
        if (threadIdx.x == 0) scount = (int)__popcll(bal);
    }
    __syncthreads();
    const int cnt = scount;

    const int ix = threadIdx.x;      // column (256 threads = 256 columns)
    const float px = pix_x(ix);
    float py[PPT];
    #pragma unroll
    for (int k = 0; k < PPT; ++k) py[k] = pix_y(tile * PPT + k);

    float bestz[PPT];
    int   bestj[PPT];
    #pragma unroll
    for (int k = 0; k < PPT; ++k) { bestz[k] = INFINITY; bestj[k] = -1; }

    for (int j = 0; j < cnt; ++j) {
        float4 q0 = sc[j][0];
        float4 q1 = sc[j][1];
        float4 q2 = sc[j][2];
        // hoist the px-dependent part (per-lane, once per face)
        float d0 = fmaf(px, q0.x, q0.z);   // A0*px + C0
        float d1 = fmaf(px, q0.w, q1.y);   // A1*px + C1
        float d2 = fmaf(px, q1.z, q2.x);   // A2*px + C2
        float dz = fmaf(px, q2.y, q2.w);   // Az*px + Cz
        #pragma unroll
        for (int k = 0; k < PPT; ++k) {
            float w0 = fmaf(q0.y, py[k], d0);
            float w1 = fmaf(q1.x, py[k], d1);
            float w2 = fmaf(q1.w, py[k], d2);
            float z  = fmaf(q2.z, py[k], dz);
            float wmin = fminf(w0, fminf(w1, w2));
            float s = fminf(z, bestz[k] - z);   // >0 iff z>0 && z<bestz
            bool cc = (wmin >= 0.0f) && (s > 0.0f);
            bestz[k] = cc ? z : bestz[k];       // strict < : first (smallest) idx on ties
            bestj[k] = cc ? j : bestj[k];
        }
    }

    unsigned long long* __restrict__ zb = zbuf + (size_t)view * NPIX;
    #pragma unroll
    for (int k = 0; k < PPT; ++k) {
        if (bestj[k] >= 0) {
            unsigned long long packed =
                ((unsigned long long)__float_as_uint(bestz[k]) << 32) |
                (unsigned int)sidx[bestj[k]];
            // lexicographic (z_bits, face_idx) min == argmin w/ first-index ties
            atomicMin(&zb[(tile * PPT + k) * IMG_S + ix], packed);
        }
    }
}

// ---- Pass 2: read merged zbuf, shade winner (bit-exact recompute), loss,
//      block-reduce, one atomicAdd per block into out (pre-zeroed) ----
__global__ __launch_bounds__(256) void shade_loss_kernel(
    const float* __restrict__ verts,
    const int*   __restrict__ faces,
    const float* __restrict__ tex,
    const float* __restrict__ ref0,
    const float* __restrict__ ref1,
    const unsigned long long* __restrict__ zbuf,
    float* __restrict__ out)
{
    __shared__ float red[4];
    const int gid  = blockIdx.x * blockDim.x + threadIdx.x;  // 0..131071
    const int view = gid >> 16;
    const int pix  = gid & (NPIX - 1);

    unsigned long long best = zbuf[(size_t)view * NPIX + pix];

    float c0 = 0.0f, c1 = 0.0f, c2 = 0.0f;
    if (best != ~0ull) {
        int fidx = (int)(best & 0xFFFFFFFFu);
        FaceCoef fcw;
        float ymin, ymax, zmax;
        compute_face_bbox(verts, faces, fidx, view, fcw, ymin, ymax, zmax);
        const float px = pix_x(pix & (IMG_S - 1));
        const float py = pix_y(pix >> 8);
        // same association as raster inner loop: fmaf(B, py, fmaf(px, A, C))
        float w0 = fmaf(fcw.B0, py, fmaf(px, fcw.A0, fcw.C0));
        float w1 = fmaf(fcw.B1, py, fmaf(px, fcw.A1, fcw.C1));
        float w2 = fmaf(fcw.B2, py, fmaf(px, fcw.A2, fcw.C2));
        int t0 = (int)fminf(fmaxf(rintf(w0 * (float)(TSZ - 1)), 0.0f), (float)(TSZ - 1));
        int t1 = (int)fminf(fmaxf(rintf(w1 * (float)(TSZ - 1)), 0.0f), (float)(TSZ - 1));
        int t2 = (int)fminf(fmaxf(rintf(w2 * (float)(TSZ - 1)), 0.0f), (float)(TSZ - 1));
        int flat = ((fidx * TSZ + t0) * TSZ + t1) * TSZ + t2;
        const float* t = tex + (long)flat * 3;
        c0 = tanhf(t[0]);
        c1 = tanhf(t[1]);
        c2 = tanhf(t[2]);
    }

    const float* __restrict__ ref = (view == 0) ? ref0 : ref1;
    float d0 = c0 - ref[0 * NPIX + pix];
    float d1 = c1 - ref[1 * NPIX + pix];
    float d2 = c2 - ref[2 * NPIX + pix];
    float acc = fmaf(d0, d0, fmaf(d1, d1, d2 * d2));

    for (int off = 32; off > 0; off >>= 1)
        acc += __shfl_down(acc, off, 64);
    int lane = threadIdx.x & 63;
    int wid = threadIdx.x >> 6;
    if (lane == 0) red[wid] = acc;
    __syncthreads();
    if (threadIdx.x == 0)
        atomicAdd(out, 0.5f * (red[0] + red[1] + red[2] + red[3]));
}

extern "C" void kernel_launch(void* const* d_in, const int* in_sizes, int n_in,
                              void* d_out, int out_size, void* d_ws, size_t ws_size,
                              hipStream_t stream) {
    const float* verts = (const float*)d_in[0];
    const int*   faces = (const int*)d_in[1];
    const float* tex   = (const float*)d_in[2];
    const float* ref0  = (const float*)d_in[3];
    const float* ref1  = (const float*)d_in[4];
    float* out = (float*)d_out;

    unsigned long long* zbuf = (unsigned long long*)d_ws;   // 2*65536*8 = 1 MB

    // init: zbuf = all-ones (== ~0ull sentinel, also max for packed min); out = 0
    hipMemsetAsync(zbuf, 0xFF, (size_t)2 * NPIX * sizeof(unsigned long long), stream);
    hipMemsetAsync(out, 0, sizeof(float), stream);

    dim3 grid1(NPIX / (256 * PPT), NCHUNK, 2);   // (32, 16, 2) = 1024 blocks
    raster_chunk_kernel<<<grid1, 256, 0, stream>>>(verts, faces, zbuf);

    const int shade_blocks = (2 * NPIX) / 256;   // 512
    shade_loss_kernel<<<shade_blocks, 256, 0, stream>>>(verts, faces, tex, ref0, ref1,
                                                        zbuf, out);
}